// Round 3
// baseline (359.374 us; speedup 1.0000x reference)
//
#include <hip/hip_runtime.h>
#include <stdint.h>

#define N_CL    8
#define C_IN    862
#define SEQ     720
#define SEQP    768            // K padded to 12 x 64 (Wb zero-padded)
#define PRED    336
#define BATCH   64
#define BK      32             // K-step per chunk
#define NCHUNK  23             // k < 736; k>=720 hits Wb zero-pad
#define NT      (PRED / 16)    // 21 n-tiles
#define XBSTRIDE ((size_t)C_IN * SEQ)

// B LDS: paired-row layout. Logical rows 0..383 (336 used), 64 B each at BK=32.
// Physical: 192 rows x 128 B; row n -> (r = n % 192, half = n / 192);
// granule g (16 B) of (n) lives at slot s = (half*4+g) ^ (r&7), byte r*128+s*16.
// 128 B physical rows + 8-slot XOR == R0's measured-zero-conflict pattern.
#define PHYSR   192
#define BBYTES  (PHYSR * 128)  // 24576 per buffer
#define NBISS   24             // 24 x 1024 B issues -> exactly 6 per wave

typedef __attribute__((ext_vector_type(8))) __bf16 bf16x8;
typedef __attribute__((ext_vector_type(4))) float  floatx4;

__device__ __forceinline__ void async16(const void* g, void* l) {
  __builtin_amdgcn_global_load_lds(
      (__attribute__((address_space(1))) unsigned int*)(uintptr_t)g,
      (__attribute__((address_space(3))) unsigned int*)l,
      16, 0, 0);
}

// ---- Kernel 1: W fp32 [8][336][720] -> bf16 [8][336][768] (zero-padded K) ----
__global__ void wconv_kernel(const float* __restrict__ W, __bf16* __restrict__ Wb) {
  const int row = blockIdx.x;                 // 0 .. 8*336-1
  const float* src = W + (size_t)row * SEQ;
  __bf16* dst = Wb + (size_t)row * SEQP;
  for (int s = threadIdx.x; s < SEQP; s += blockDim.x) {
    float v = (s < SEQ) ? src[s] : 0.0f;
    dst[s] = (__bf16)v;
  }
}

// ---- Kernel 2: per-channel GEMM. B double-buffered in LDS (counted vmcnt,
//      conflict-free paired-row swizzle), A in registers prefetched 2 ahead.
//      Main loop FULLY UNROLLED: no reg-rotation movs -> compiler inserts no
//      pipeline-draining waitcnts (the R2 failure mode). ----
__global__ __launch_bounds__(256, 3) void clin_kernel(
    const float* __restrict__ x, const int* __restrict__ clusters,
    const __bf16* __restrict__ Wb, const float* __restrict__ bias,
    float* __restrict__ out) {
  __shared__ __attribute__((aligned(128))) unsigned char smem[2 * BBYTES];

  const int c    = blockIdx.x;
  const int cl   = clusters[c];
  const int tid  = threadIdx.x;
  const int wave = tid >> 6;
  const int lane = tid & 63;
  const int q    = lane >> 4;     // quad 0..3 -> k-granule of the 32-wide step
  const int ln   = lane & 15;     // lane-in-quad -> m-row (A) / n-col (B)

  const int mrow  = (wave << 4) + ln;   // batch row 0..63
  const int klane = q << 3;             // per-lane k offset (elements)

  const float*  xr = x  + (size_t)mrow * XBSTRIDE + (size_t)c * SEQ + klane;
  const __bf16* wc = Wb + (size_t)cl * PRED * SEQP;

  // ---- staging constants: issue i covers physical rows i*8..i*8+7 ----
  // lane -> (phys row r = i*8 + (lane>>3), slot s = lane&7).
  // Invert swizzle: c2 = s ^ (r&7) = (lane&7) ^ (lane>>3); half = c2>>2, g = c2&3.
  const int s_c2   = (lane & 7) ^ (lane >> 3);
  const int s_g    = s_c2 & 3;                       // source k-granule
  const int s_nb   = (lane >> 3) + 192 * (s_c2 >> 2); // logical row base (+ i*8)

  // ---- read constants: tile tt, row n = tt*16+ln, addr = r*128 + slot*16 ----
  const int e    = ln & 7;
  const int brd0 = ln * 128 + (((q    ) ^ e) << 4);           // half 0 (tt<12)
  const int brd1 = ln * 128 + (((q + 4) ^ e) << 4) - 24576;   // half 1 (tt>=12)

  floatx4 acc[NT];
#pragma unroll
  for (int t = 0; t < NT; ++t) acc[t] = (floatx4){0.f, 0.f, 0.f, 0.f};

#define STAGE_B(k0, Bdst)                                                     \
  {                                                                           \
    _Pragma("unroll")                                                         \
    for (int i = wave; i < NBISS; i += 4) {                                   \
      int n  = (i << 3) + s_nb;                                               \
      int ns = (n < PRED) ? n : 0;   /* pad rows: any valid addr, never read */\
      async16(wc + (size_t)ns * SEQP + (k0) + (s_g << 3), (Bdst) + i * 1024); \
    }                                                                         \
  }

  // A tail: clamp ADDRESS for k>=720 lanes; their garbage meets Wb's zero-pad
  // (product 0). Loads always issue -> vmcnt stays uniform per wave.
#define LOAD_A(k0, f0, f1)                                                    \
  {                                                                           \
    const float* ap = ((k0) + klane < SEQ) ? (xr + (k0)) : xr;                \
    f0 = *(const floatx4*)ap;                                                 \
    f1 = *(const floatx4*)(ap + 4);                                           \
  }

#define COMPUTE(Bsrc, f0, f1)                                                 \
  {                                                                           \
    bf16x8 a;                                                                 \
    a[0] = (__bf16)f0[0]; a[1] = (__bf16)f0[1];                               \
    a[2] = (__bf16)f0[2]; a[3] = (__bf16)f0[3];                               \
    a[4] = (__bf16)f1[0]; a[5] = (__bf16)f1[1];                               \
    a[6] = (__bf16)f1[2]; a[7] = (__bf16)f1[3];                               \
    _Pragma("unroll")                                                         \
    for (int tt = 0; tt < NT; ++tt) {                                         \
      int off = tt * 2048 + (tt < 12 ? brd0 : brd1);                          \
      bf16x8 b = *(const bf16x8*)((Bsrc) + off);                              \
      acc[tt] = __builtin_amdgcn_mfma_f32_16x16x32_bf16(a, b, acc[tt], 0, 0, 0); \
    }                                                                         \
  }

  unsigned char* const B0 = smem;
  unsigned char* const B1 = smem + BBYTES;

  // A register queue, depth 3 (current + 2 prefetched). Full unroll keeps these
  // in SSA form -> no copies -> no compiler-inserted tight vmcnt.
  floatx4 a0[NCHUNK + 2], a1[NCHUNK + 2];   // indexed by compile-time constants only

  // ---- prologue: B(0) staged, A(0), A(1) issued ----
  STAGE_B(0, B0);
  __builtin_amdgcn_sched_barrier(0);
  LOAD_A(0, a0[0], a1[0]);
  LOAD_A(BK, a0[1], a1[1]);
  __builtin_amdgcn_sched_barrier(0);

  // ---- main loop (fully unrolled): compute chunk t, prefetch B(t+1), A(t+2) ----
#pragma unroll
  for (int t = 0; t < NCHUNK - 1; ++t) {
    unsigned char* Bc = (t & 1) ? B1 : B0;
    unsigned char* Bn = (t & 1) ? B0 : B1;

    STAGE_B((t + 1) * BK, Bn);                    // 6 issues/wave
    __builtin_amdgcn_sched_barrier(0);
    LOAD_A((t + 2) * BK, a0[t + 2], a1[t + 2]);   // 2 loads/wave
    __builtin_amdgcn_sched_barrier(0);

    // Drain through B(t) (+A(t), A(t+1) already resident); leave the newest
    // 8 (B(t+1)+A(t+2)) plus A(t+1)'s 2 = 10 in flight across the barriers.
    asm volatile("s_waitcnt vmcnt(10)" ::: "memory");
    __builtin_amdgcn_s_barrier();

    COMPUTE(Bc, a0[t], a1[t]);

    __builtin_amdgcn_s_barrier();   // all waves done with Bc before t+2 overwrites
  }

  // ---- last chunk: nothing behind it, full drain is fine ----
  asm volatile("s_waitcnt vmcnt(0)" ::: "memory");
  __builtin_amdgcn_s_barrier();
  {
    unsigned char* Bc = ((NCHUNK - 1) & 1) ? B1 : B0;
    COMPUTE(Bc, a0[NCHUNK - 1], a1[NCHUNK - 1]);
  }

  // ---- epilogue: bias add + store. C/D layout: col=ln (p), row=q*4+r (batch) ----
  const float* bc = bias + cl * PRED;
#pragma unroll
  for (int t = 0; t < NT; ++t) {
    int p = (t << 4) + ln;
    float bv = bc[p];
#pragma unroll
    for (int r = 0; r < 4; ++r) {
      int brow = (wave << 4) + (q << 2) + r;    // batch index
      out[((size_t)brow * C_IN + c) * PRED + p] = acc[t][r] + bv;
    }
  }
#undef STAGE_B
#undef LOAD_A
#undef COMPUTE
}

extern "C" void kernel_launch(void* const* d_in, const int* in_sizes, int n_in,
                              void* d_out, int out_size, void* d_ws, size_t ws_size,
                              hipStream_t stream) {
  const float* x   = (const float*)d_in[0];
  const int*   cls = (const int*)d_in[1];
  const float* W   = (const float*)d_in[2];
  const float* b   = (const float*)d_in[3];
  float* out = (float*)d_out;
  __bf16* Wb = (__bf16*)d_ws;   // 8*336*768*2 = 4,128,768 B

  hipLaunchKernelGGL(wconv_kernel, dim3(N_CL * PRED), dim3(256), 0, stream, W, Wb);
  hipLaunchKernelGGL(clin_kernel, dim3(C_IN), dim3(256), 0, stream,
                     x, cls, Wb, b, out);
}

// Round 4
// 357.384 us; speedup vs baseline: 1.0056x; 1.0056x over previous
//
#include <hip/hip_runtime.h>
#include <stdint.h>

#define N_CL    8
#define C_IN    862
#define SEQ     720
#define SEQP    768            // K padded to 12 x 64 (Wb zero-padded)
#define PRED    336
#define BATCH   64
#define BK      32             // K-step per chunk
#define NCHUNK  23             // k < 736; k>=720 hits Wb zero-pad
#define NT      (PRED / 16)    // 21 n-tiles
#define XBSTRIDE ((size_t)C_IN * SEQ)

// B LDS: paired-row layout (R3, measured zero-conflict).
// Physical: 192 rows x 128 B; logical row n -> (r = n % 192, half = n / 192);
// granule g (16 B) of n lives at slot s = (half*4+g) ^ (r&7), byte r*128+s*16.
#define PHYSR   192
#define BBYTES  (PHYSR * 128)  // 24576 per buffer
#define NBISS   24             // 24 x 1024 B issues -> exactly 6 per wave

typedef __attribute__((ext_vector_type(8))) __bf16 bf16x8;
typedef __attribute__((ext_vector_type(4))) float  floatx4;

__device__ __forceinline__ void async16(const void* g, void* l) {
  __builtin_amdgcn_global_load_lds(
      (__attribute__((address_space(1))) unsigned int*)(uintptr_t)g,
      (__attribute__((address_space(3))) unsigned int*)l,
      16, 0, 0);
}

// ---- Kernel 1: W fp32 [8][336][720] -> bf16 [8][336][768] (zero-padded K) ----
__global__ void wconv_kernel(const float* __restrict__ W, __bf16* __restrict__ Wb) {
  const int row = blockIdx.x;                 // 0 .. 8*336-1
  const float* src = W + (size_t)row * SEQ;
  __bf16* dst = Wb + (size_t)row * SEQP;
  for (int s = threadIdx.x; s < SEQP; s += blockDim.x) {
    float v = (s < SEQ) ? src[s] : 0.0f;
    dst[s] = (__bf16)v;
  }
}

// ---- Kernel 2: per-channel GEMM. B double-buffered in LDS (counted vmcnt,
//      zero-conflict paired-row swizzle). A prefetched depth-2 in TWO NAMED
//      register pairs (parity scheme, no arrays -> no scratch, the R3 killer).
//      Main loop = 22 hand-stamped iterations; A(t+2) is loaded AFTER
//      COMPUTE(t) frees slot t%2, so two slots suffice with zero copies. ----
__global__ __launch_bounds__(256, 3) void clin_kernel(
    const float* __restrict__ x, const int* __restrict__ clusters,
    const __bf16* __restrict__ Wb, const float* __restrict__ bias,
    float* __restrict__ out) {
  __shared__ __attribute__((aligned(128))) unsigned char smem[2 * BBYTES];

  const int c    = blockIdx.x;
  const int cl   = clusters[c];
  const int tid  = threadIdx.x;
  const int wave = tid >> 6;
  const int lane = tid & 63;
  const int q    = lane >> 4;     // quad 0..3 -> k-granule of the 32-wide step
  const int ln   = lane & 15;     // lane-in-quad -> m-row (A) / n-col (B)

  const int mrow  = (wave << 4) + ln;   // batch row 0..63
  const int klane = q << 3;             // per-lane k offset (elements)

  const float*  xr = x  + (size_t)mrow * XBSTRIDE + (size_t)c * SEQ + klane;
  const __bf16* wc = Wb + (size_t)cl * PRED * SEQP;

  // staging: issue i covers physical rows i*8..i*8+7; lane -> (r=i*8+(lane>>3),
  // slot=lane&7). Inverse swizzle: c2 = (lane&7)^(lane>>3); half=c2>>2, g=c2&3.
  const int s_c2 = (lane & 7) ^ (lane >> 3);
  const int s_g  = s_c2 & 3;                          // source k-granule
  const int s_nb = (lane >> 3) + 192 * (s_c2 >> 2);   // logical row base (+ i*8)

  // read: tile tt, row n = tt*16+ln -> phys r = n%192, slot = (half*4+q)^(r&7)
  const int e    = ln & 7;
  const int brd0 = ln * 128 + (((q    ) ^ e) << 4);           // half 0 (tt<12)
  const int brd1 = ln * 128 + (((q + 4) ^ e) << 4) - 24576;   // half 1 (tt>=12)

  floatx4 acc[NT];
#pragma unroll
  for (int t = 0; t < NT; ++t) acc[t] = (floatx4){0.f, 0.f, 0.f, 0.f};

#define STAGE_B(k0, Bdst)                                                     \
  {                                                                           \
    _Pragma("unroll")                                                         \
    for (int i = wave; i < NBISS; i += 4) {                                   \
      int n  = (i << 3) + s_nb;                                               \
      int ns = (n < PRED) ? n : 0;   /* pad rows: valid addr, never read */   \
      async16(wc + (size_t)ns * SEQP + (k0) + (s_g << 3), (Bdst) + i * 1024); \
    }                                                                         \
  }

  // A tail: clamp ADDRESS when the lane's 8-float span starts >= 720 (720%8==0
  // so spans never straddle); garbage meets Wb's zero-pad -> product 0.
  // Loads always issue -> per-wave vmcnt stays uniform.
#define LOAD_A(k0, f0, f1)                                                    \
  {                                                                           \
    const float* ap = ((k0) + klane < SEQ) ? (xr + (k0)) : xr;                \
    f0 = *(const floatx4*)ap;                                                 \
    f1 = *(const floatx4*)(ap + 4);                                           \
  }

#define COMPUTE(Bsrc, f0, f1)                                                 \
  {                                                                           \
    bf16x8 a;                                                                 \
    a[0] = (__bf16)f0[0]; a[1] = (__bf16)f0[1];                               \
    a[2] = (__bf16)f0[2]; a[3] = (__bf16)f0[3];                               \
    a[4] = (__bf16)f1[0]; a[5] = (__bf16)f1[1];                               \
    a[6] = (__bf16)f1[2]; a[7] = (__bf16)f1[3];                               \
    _Pragma("unroll")                                                         \
    for (int tt = 0; tt < NT; ++tt) {                                         \
      int off = tt * 2048 + (tt < 12 ? brd0 : brd1);                          \
      bf16x8 b = *(const bf16x8*)((Bsrc) + off);                              \
      acc[tt] = __builtin_amdgcn_mfma_f32_16x16x32_bf16(a, b, acc[tt], 0, 0, 0); \
    }                                                                         \
  }

  unsigned char* const B0 = smem;
  unsigned char* const B1 = smem + BBYTES;

  floatx4 aA0, aA1, aB0, aB1;   // two named A slots: even chunks in aA, odd in aB

  // ---- prologue: B(0)->B0, A(0)->aA, A(1)->aB  (10 vmem ops in flight) ----
  STAGE_B(0, B0);
  __builtin_amdgcn_sched_barrier(0);
  LOAD_A(0, aA0, aA1);
  LOAD_A(BK, aB0, aB1);
  __builtin_amdgcn_sched_barrier(0);

  // Iteration t: stage B(t+1) [6], wait vmcnt(8) (drains B(t)+A(t); leaves
  // A(t+1)+B(t+1)=8 in flight), barrier, compute chunk t, then reload slot
  // t%2 with A(t+2), barrier. No copies, no arrays, counts exact.
#define ITER(t, ac0, ac1, Bc, Bn)                                             \
  STAGE_B((t + 1) * BK, Bn);                                                  \
  __builtin_amdgcn_sched_barrier(0);                                          \
  asm volatile("s_waitcnt vmcnt(8)" ::: "memory");                            \
  __builtin_amdgcn_s_barrier();                                               \
  COMPUTE(Bc, ac0, ac1);                                                      \
  __builtin_amdgcn_sched_barrier(0);                                          \
  LOAD_A((t + 2) * BK, ac0, ac1);                                             \
  __builtin_amdgcn_sched_barrier(0);                                          \
  __builtin_amdgcn_s_barrier();

  ITER( 0, aA0, aA1, B0, B1)
  ITER( 1, aB0, aB1, B1, B0)
  ITER( 2, aA0, aA1, B0, B1)
  ITER( 3, aB0, aB1, B1, B0)
  ITER( 4, aA0, aA1, B0, B1)
  ITER( 5, aB0, aB1, B1, B0)
  ITER( 6, aA0, aA1, B0, B1)
  ITER( 7, aB0, aB1, B1, B0)
  ITER( 8, aA0, aA1, B0, B1)
  ITER( 9, aB0, aB1, B1, B0)
  ITER(10, aA0, aA1, B0, B1)
  ITER(11, aB0, aB1, B1, B0)
  ITER(12, aA0, aA1, B0, B1)
  ITER(13, aB0, aB1, B1, B0)
  ITER(14, aA0, aA1, B0, B1)
  ITER(15, aB0, aB1, B1, B0)
  ITER(16, aA0, aA1, B0, B1)
  ITER(17, aB0, aB1, B1, B0)
  ITER(18, aA0, aA1, B0, B1)
  ITER(19, aB0, aB1, B1, B0)
  ITER(20, aA0, aA1, B0, B1)
  ITER(21, aB0, aB1, B1, B0)

  // ---- last chunk 22 (staged at ITER 21 into B0; A(22) in aA from ITER 20) ----
  asm volatile("s_waitcnt vmcnt(0)" ::: "memory");
  __builtin_amdgcn_s_barrier();
  COMPUTE(B0, aA0, aA1);

  // ---- epilogue: bias add + store. C/D layout: col=ln (p), row=q*4+r (batch) ----
  const float* bc = bias + cl * PRED;
#pragma unroll
  for (int t = 0; t < NT; ++t) {
    int p = (t << 4) + ln;
    float bv = bc[p];
#pragma unroll
    for (int r = 0; r < 4; ++r) {
      int brow = (wave << 4) + (q << 2) + r;    // batch index
      out[((size_t)brow * C_IN + c) * PRED + p] = acc[t][r] + bv;
    }
  }
#undef STAGE_B
#undef LOAD_A
#undef COMPUTE
#undef ITER
}

extern "C" void kernel_launch(void* const* d_in, const int* in_sizes, int n_in,
                              void* d_out, int out_size, void* d_ws, size_t ws_size,
                              hipStream_t stream) {
  const float* x   = (const float*)d_in[0];
  const int*   cls = (const int*)d_in[1];
  const float* W   = (const float*)d_in[2];
  const float* b   = (const float*)d_in[3];
  float* out = (float*)d_out;
  __bf16* Wb = (__bf16*)d_ws;   // 8*336*768*2 = 4,128,768 B

  hipLaunchKernelGGL(wconv_kernel, dim3(N_CL * PRED), dim3(256), 0, stream, W, Wb);
  hipLaunchKernelGGL(clin_kernel, dim3(C_IN), dim3(256), 0, stream,
                     x, cls, Wb, b, out);
}

// Round 5
// 301.787 us; speedup vs baseline: 1.1908x; 1.1842x over previous
//
#include <hip/hip_runtime.h>
#include <stdint.h>

#define N_CL    8
#define C_IN    862
#define SEQ     720
#define SEQP    768            // K padded to 12 x 64 (Wb zero-padded)
#define PRED    336
#define BATCH   64
#define BK      64             // K-step per phase -> 12 phases
#define NPH     12
#define NT      (PRED / 16)    // 21 n-tiles
#define XBSTRIDE ((size_t)C_IN * SEQ)

// B LDS: 336 rows x 128 B (BK=64 bf16), 16B-granule XOR swizzle slot = g ^ (n&7).
// This is R0's measured-zero-conflict layout. Single buffer: 43008 B -> 3 blocks/CU.
#define BBYTES  (PRED * 128)   // 43008
#define NBISS   42             // 42 x 1024 B staging issues per phase

typedef __attribute__((ext_vector_type(8))) __bf16 bf16x8;
typedef __attribute__((ext_vector_type(4))) float  floatx4;

__device__ __forceinline__ void async16(const void* g, void* l) {
  __builtin_amdgcn_global_load_lds(
      (__attribute__((address_space(1))) unsigned int*)(uintptr_t)g,
      (__attribute__((address_space(3))) unsigned int*)l,
      16, 0, 0);
}

// ---- Kernel 1: W fp32 [8][336][720] -> bf16 [8][336][768] (zero-padded K) ----
__global__ void wconv_kernel(const float* __restrict__ W, __bf16* __restrict__ Wb) {
  const int row = blockIdx.x;                 // 0 .. 8*336-1
  const float* src = W + (size_t)row * SEQ;
  __bf16* dst = Wb + (size_t)row * SEQP;
  for (int s = threadIdx.x; s < SEQP; s += blockDim.x) {
    float v = (s < SEQ) ? src[s] : 0.0f;
    dst[s] = (__bf16)v;
  }
}

// ---- Kernel 2: per-channel GEMM. BK=64, 12 phases (phase cost is ~constant:
//      minimize phase count). B single-buffered in LDS (42 KB -> 3 blocks/CU),
//      R0's zero-conflict layout. A in named parity registers, prefetched one
//      phase ahead; counted vmcnt(4) drains only B, keeps A(t+1) in flight.
//      Rolled x2 loop: small code (R3/R4's full unroll regressed). ----
__global__ __launch_bounds__(256, 3) void clin_kernel(
    const float* __restrict__ x, const int* __restrict__ clusters,
    const __bf16* __restrict__ Wb, const float* __restrict__ bias,
    float* __restrict__ out) {
  __shared__ __attribute__((aligned(128))) unsigned char Bs[BBYTES];

  const int c    = blockIdx.x;
  const int cl   = clusters[c];
  const int tid  = threadIdx.x;
  const int wave = tid >> 6;
  const int lane = tid & 63;
  const int q    = lane >> 4;     // quad 0..3 -> k-subgroup (k offset q*8 per 32-step)
  const int ln   = lane & 15;     // lane-in-quad -> m-row (A) / n-col (B)

  const int mrow  = (wave << 4) + ln;   // batch row 0..63
  const int klane = q << 3;             // per-lane k offset (elements)

  const float*  xr = x  + (size_t)mrow * XBSTRIDE + (size_t)c * SEQ + klane;
  const __bf16* wc = Wb + (size_t)cl * PRED * SEQP;

  // Staging: issue i covers rows i*8..i*8+7 (8 rows x 128 B = 1024 B).
  // lane -> row i*8 + (lane>>3), slot lane&7; logical granule lg = slot ^ (row&7)
  // is lane-constant since row&7 == lane>>3.
  const int lg = (lane & 7) ^ (lane >> 3);
  const __bf16* wsrc = wc + (size_t)(lane >> 3) * SEQP + (lg << 3);

  // Read: tile tt, row n = tt*16+ln, k-substep kk in {0,32}: granule (kk>>3)+q,
  // slot = granule ^ (n&7); n&7 == ln&7.
  const int e     = ln & 7;
  const int brd_k0 = ln * 128 + (((0 + q) ^ e) << 4);
  const int brd_k1 = ln * 128 + (((4 + q) ^ e) << 4);

  floatx4 acc[NT];
#pragma unroll
  for (int t = 0; t < NT; ++t) acc[t] = (floatx4){0.f, 0.f, 0.f, 0.f};

#define STAGE_B(k0)                                                           \
  {                                                                           \
    _Pragma("unroll")                                                         \
    for (int i = wave; i < NBISS; i += 4)                                     \
      async16(wsrc + (size_t)i * 8 * SEQP + (k0), Bs + i * 1024);             \
  }

  // A loads for phase at k0: two bf16x8 frags worth of fp32 (k0+klane.. and
  // k0+32+klane..). Tail phases clamp the ADDRESS (spans never straddle 720
  // since 720%8==0); garbage values meet Wb's zero-pad -> product 0.
  // Loads always issue -> per-wave vmcnt uniform.
#define LOAD_A(k0, f00, f01, f10, f11)                                        \
  {                                                                           \
    const float* ap0 = ((k0) + klane < SEQ) ? (xr + (k0)) : xr;               \
    const float* ap1 = ((k0) + 32 + klane < SEQ) ? (xr + (k0) + 32) : xr;     \
    f00 = *(const floatx4*)ap0;  f01 = *(const floatx4*)(ap0 + 4);            \
    f10 = *(const floatx4*)ap1;  f11 = *(const floatx4*)(ap1 + 4);            \
  }

#define COMPUTE(f00, f01, f10, f11)                                           \
  {                                                                           \
    bf16x8 a0, a1;                                                            \
    a0[0] = (__bf16)f00[0]; a0[1] = (__bf16)f00[1];                           \
    a0[2] = (__bf16)f00[2]; a0[3] = (__bf16)f00[3];                           \
    a0[4] = (__bf16)f01[0]; a0[5] = (__bf16)f01[1];                           \
    a0[6] = (__bf16)f01[2]; a0[7] = (__bf16)f01[3];                           \
    a1[0] = (__bf16)f10[0]; a1[1] = (__bf16)f10[1];                           \
    a1[2] = (__bf16)f10[2]; a1[3] = (__bf16)f10[3];                           \
    a1[4] = (__bf16)f11[0]; a1[5] = (__bf16)f11[1];                           \
    a1[6] = (__bf16)f11[2]; a1[7] = (__bf16)f11[3];                           \
    _Pragma("unroll")                                                         \
    for (int tt = 0; tt < NT; ++tt) {                                         \
      bf16x8 b = *(const bf16x8*)(Bs + tt * 2048 + brd_k0);                   \
      acc[tt] = __builtin_amdgcn_mfma_f32_16x16x32_bf16(a0, b, acc[tt], 0, 0, 0); \
    }                                                                         \
    _Pragma("unroll")                                                         \
    for (int tt = 0; tt < NT; ++tt) {                                         \
      bf16x8 b = *(const bf16x8*)(Bs + tt * 2048 + brd_k1);                   \
      acc[tt] = __builtin_amdgcn_mfma_f32_16x16x32_bf16(a1, b, acc[tt], 0, 0, 0); \
    }                                                                         \
  }

  // Phase t: stage B(t) (10-11 issues/wave), issue A(t+1) (4 loads), then
  // vmcnt(4): drains this wave's B(t) (and the old A(t), issued last phase),
  // leaves A(t+1)'s 4 in flight across the barrier. Barrier -> all waves'
  // staging landed. Compute. Barrier (reads done before next overwrite).
#define PHASE(k0, c00, c01, c10, c11, n00, n01, n10, n11)                     \
  STAGE_B(k0);                                                                \
  LOAD_A((k0) + BK, n00, n01, n10, n11);                                      \
  asm volatile("s_waitcnt vmcnt(4)" ::: "memory");                            \
  __builtin_amdgcn_s_barrier();                                               \
  COMPUTE(c00, c01, c10, c11);                                                \
  __builtin_amdgcn_s_barrier();

  floatx4 A00, A01, A10, A11, B00, B01, B10, B11;

  LOAD_A(0, A00, A01, A10, A11);

  for (int t = 0; t < NPH; t += 2) {
    const int k0 = t * BK;
    PHASE(k0,      A00, A01, A10, A11, B00, B01, B10, B11)
    PHASE(k0 + BK, B00, B01, B10, B11, A00, A01, A10, A11)
  }

  // ---- epilogue: bias add + store. C/D layout: col=ln (p), row=q*4+r (batch) ----
  const float* bc = bias + cl * PRED;
#pragma unroll
  for (int t = 0; t < NT; ++t) {
    int p = (t << 4) + ln;
    float bv = bc[p];
#pragma unroll
    for (int r = 0; r < 4; ++r) {
      int brow = (wave << 4) + (q << 2) + r;    // batch index
      out[((size_t)brow * C_IN + c) * PRED + p] = acc[t][r] + bv;
    }
  }
#undef STAGE_B
#undef LOAD_A
#undef COMPUTE
#undef PHASE
}

extern "C" void kernel_launch(void* const* d_in, const int* in_sizes, int n_in,
                              void* d_out, int out_size, void* d_ws, size_t ws_size,
                              hipStream_t stream) {
  const float* x   = (const float*)d_in[0];
  const int*   cls = (const int*)d_in[1];
  const float* W   = (const float*)d_in[2];
  const float* b   = (const float*)d_in[3];
  float* out = (float*)d_out;
  __bf16* Wb = (__bf16*)d_ws;   // 8*336*768*2 = 4,128,768 B

  hipLaunchKernelGGL(wconv_kernel, dim3(N_CL * PRED), dim3(256), 0, stream, W, Wb);
  hipLaunchKernelGGL(clin_kernel, dim3(C_IN), dim3(256), 0, stream,
                     x, cls, Wb, b, out);
}